// Round 14
// baseline (323.227 us; speedup 1.0000x reference)
//
#include <hip/hip_runtime.h>
#include <hip/hip_bf16.h>
#include <cstdint>

typedef __hip_bfloat16 bf16;

constexpr int Bb = 16, Nn = 128, Ll = 512, Dd = 1024, Ss = 16, Rr = 64, Hh = 2048;
constexpr int Mm = Bb * Nn; // 2048 rows
#define LOG2E 1.44269504088896340736f

using bf16x8 = __attribute__((ext_vector_type(8))) __bf16;
using bf16x4 = __attribute__((ext_vector_type(4))) __bf16;
using f32x4  = __attribute__((ext_vector_type(4))) float;

__device__ __forceinline__ float to_f(float x) { return x; }
__device__ __forceinline__ float to_f(bf16 x) { return __bfloat162float(x); }
__device__ __forceinline__ void store_t(float* p, float v) { *p = v; }
__device__ __forceinline__ void store_t(bf16* p, float v) { *p = __float2bfloat16(v); }
__device__ __forceinline__ __bf16 cvt1(float x) {
  bf16 h = __float2bfloat16(x);
  return *reinterpret_cast<__bf16*>(&h);
}
__device__ __forceinline__ float bfraw_to_f(__bf16 x) {
  bf16 h = *reinterpret_cast<bf16*>(&x);
  return __bfloat162float(h);
}
__device__ __forceinline__ bf16x8 load8(const bf16* p) { return *(const bf16x8*)p; }
__device__ __forceinline__ bf16x8 load8(const float* p) {
  float4 a = *(const float4*)p;
  float4 b = *(const float4*)(p + 4);
  bf16x8 r;
  r[0] = cvt1(a.x); r[1] = cvt1(a.y); r[2] = cvt1(a.z); r[3] = cvt1(a.w);
  r[4] = cvt1(b.x); r[5] = cvt1(b.y); r[6] = cvt1(b.z); r[7] = cvt1(b.w);
  return r;
}
__device__ __forceinline__ bf16x8 load8rt(const void* p, size_t idx, int isbf) {
  if (isbf) return load8((const bf16*)p + idx);
  return load8((const float*)p + idx);
}
__device__ __forceinline__ float ldf(const void* p, int i, int isbf) {
  if (isbf) return __bfloat162float(((const bf16*)p)[i]);
  return ((const float*)p)[i];
}
// async global->LDS 16B: dest = wave-uniform base + lane*16
__device__ __forceinline__ void gld16(const bf16* g, __bf16* l) {
  __builtin_amdgcn_global_load_lds(
      (const __attribute__((address_space(1))) void*)g,
      (__attribute__((address_space(3))) void*)l, 16, 0, 0);
}
// quad butterfly via DPP (VALU pipe)
#if __has_builtin(__builtin_amdgcn_mov_dpp)
__device__ __forceinline__ float quad_xor1(float v) {
  int r = __builtin_amdgcn_mov_dpp(__builtin_bit_cast(int, v), 0xB1, 0xF, 0xF, true);
  return __builtin_bit_cast(float, r);
}
__device__ __forceinline__ float quad_xor2(float v) {
  int r = __builtin_amdgcn_mov_dpp(__builtin_bit_cast(int, v), 0x4E, 0xF, 0xF, true);
  return __builtin_bit_cast(float, r);
}
#else
__device__ __forceinline__ float quad_xor1(float v) { return __shfl_xor(v, 1, 64); }
__device__ __forceinline__ float quad_xor2(float v) { return __shfl_xor(v, 2, 64); }
#endif
// lane-bit-5 exchange on VALU (verified compiles+passes: R10/v12)
__device__ __forceinline__ float lane32_other(float a, int lane) {
#if __has_builtin(__builtin_amdgcn_permlane32_swap)
  unsigned au = __builtin_bit_cast(unsigned, a);
  auto pr = __builtin_amdgcn_permlane32_swap(au, au, false, false);
  return __builtin_bit_cast(float, (lane & 32) ? pr[0] : pr[1]);
#else
  return __shfl_xor(a, 32, 64);
#endif
}

enum { EPI_STORE = 0, EPI_BIAS_RELU = 1, EPI_ADD = 3, EPI_BIAS = 4, EPI_BIAS_SOFTPLUS = 5,
       EPI_ATOMIC = 6 };

// ---- dtype sniffer (trusted) ----------------------------------------------
__global__ void sniff_kernel(const unsigned short* __restrict__ xs, int* __restrict__ flags) {
  const int tid = threadIdx.x;
  int cnt = 0;
  for (int j = 0; j < 64; ++j) {
    int i = tid + j * 256;
    unsigned short u = xs[(size_t)i * 64];
    bf16 h = *reinterpret_cast<bf16*>(&u);
    float v = __bfloat162float(h);
    float a = fabsf(v);
    if (v == 0.f || (a > 0.0009765625f && a < 16.f)) ++cnt;
  }
  __shared__ int sc[256];
  sc[tid] = cnt;
  __syncthreads();
  for (int o = 128; o > 0; o >>= 1) {
    if (tid < o) sc[tid] += sc[tid + o];
    __syncthreads();
  }
  if (tid == 0) flags[0] = (sc[0] > 8192) ? 1 : 0; // 1 = bf16, 0 = f32
}

// ---- prep: ZB=f32(x), Xb=bf16(x), zero DBC|Z2, materialize bf16 weights ----
__global__ __launch_bounds__(256) void prep_kernel(
    const int* __restrict__ flagp, const void* __restrict__ x,
    float* __restrict__ ZB, unsigned short* __restrict__ Xb,
    float* __restrict__ zerop,
    const void* __restrict__ fin, const void* __restrict__ rin,
    const void* __restrict__ fout, const void* __restrict__ rout,
    const void* __restrict__ puw, const void* __restrict__ plw,
    bf16* __restrict__ WBin, bf16* __restrict__ WBout,
    bf16* __restrict__ WBpu, bf16* __restrict__ WBpl) {
  const int isbf = *flagp;
  const int i = blockIdx.x * 256 + threadIdx.x;
  if (i < 262144) { // ZB + Xb (4 el)
    float4 o;
    ushort4 u;
    if (isbf) {
      u = ((const ushort4*)x)[i];
      bf16 h0 = *reinterpret_cast<bf16*>(&u.x), h1 = *reinterpret_cast<bf16*>(&u.y);
      bf16 h2 = *reinterpret_cast<bf16*>(&u.z), h3 = *reinterpret_cast<bf16*>(&u.w);
      o = float4{__bfloat162float(h0), __bfloat162float(h1),
                 __bfloat162float(h2), __bfloat162float(h3)};
    } else {
      o = ((const float4*)x)[i];
      bf16 h0 = __float2bfloat16(o.x), h1 = __float2bfloat16(o.y);
      bf16 h2 = __float2bfloat16(o.z), h3 = __float2bfloat16(o.w);
      u = ushort4{*(unsigned short*)&h0, *(unsigned short*)&h1,
                  *(unsigned short*)&h2, *(unsigned short*)&h3};
    }
    ((float4*)ZB)[i] = o;
    ((ushort4*)Xb)[i] = u;
  } else if (i < 622592) { // zero DBC|Z2
    ((float4*)zerop)[i - 262144] = float4{0.f, 0.f, 0.f, 0.f};
  } else { // weights, 8-el chunks
    const int j = i - 622592;
    const void* src;
    bf16* dst;
    int si;
    if (j < 131072) { src = fin; si = j; dst = WBin + (size_t)si * 8; }
    else if (j < 262144) { src = rin; si = j - 131072; dst = WBin + (size_t)1048576 + (size_t)si * 8; }
    else if (j < 393216) { src = puw; si = j - 262144; dst = WBpu + (size_t)si * 8; }
    else if (j < 524288) { src = plw; si = j - 393216; dst = WBpl + (size_t)si * 8; }
    else if (j < 589824) { // f_out [512][1024] -> WBout[n][0..1023]
      src = fout; si = j - 524288;
      int e = si * 8;
      dst = WBout + (size_t)(e >> 10) * 2048 + (e & 1023);
    } else {               // r_out [512][1024] -> WBout[n][1024..2047]
      src = rout; si = j - 589824;
      int e = si * 8;
      dst = WBout + (size_t)(e >> 10) * 2048 + 1024 + (e & 1023);
    }
    *(bf16x8*)dst = load8rt(src, (size_t)si * 8, isbf);
  }
}

constexpr int LDT2 = 72; // anti-conflict row stride (144 B)

// ---- MFMA GEMM 64x64 tile (trusted core): xproj ---------------------------
template <typename TC, int EPI>
__global__ __launch_bounds__(256) void gemm_rt(
    const int* __restrict__ flagp,
    const void* __restrict__ A, int lda, int abf,
    const void* __restrict__ Bw, const void* __restrict__ Bw2, int ldb,
    int bmode, int bsplit,
    TC* __restrict__ C, int ldc,
    const void* __restrict__ bias, const void* __restrict__ bias2,
    int N, int Kchunk, int zk, size_t a_doff, size_t c_doff) {
  const int isbf = *flagp;
  const int ab = (abf == 2) ? isbf : abf;
  __shared__ __align__(16) __bf16 As[64 * LDT2];
  __shared__ __align__(16) __bf16 Bs[64 * LDT2];
  const int tid = threadIdx.x;
  const int wave = tid >> 6, lane = tid & 63;
  const int quad = lane >> 4, l16 = lane & 15;
  const int wm = wave & 1, wn = wave >> 1;
  int bx = blockIdx.x, by = blockIdx.y;
  const int gx = gridDim.x, gy = gridDim.y;
  if ((gx & 7) == 0) {
    int id = bx + gx * by;
    int xcd = id & 7, sl = id >> 3;
    by = sl % gy;
    bx = (sl / gy) * 8 + xcd;
  }
  int zsl = blockIdx.z;
  const void* Ap = A;
  const void* Bp0 = Bw;
  const void* biasp = bias;
  if (bmode == 3) {
    const int dir = zsl / zk;
    zsl = zsl % zk;
    if (dir) {
      Ap = (const char*)A + a_doff * (size_t)(ab ? 2 : 4);
      C += c_doff;
      Bp0 = Bw2;
      biasp = bias2;
    }
  }
  const int m0 = by * 64, n0 = bx * 64;
  const int kb = zsl * Kchunk;
  const int srow = tid >> 3;
  const int scol = (tid & 7) * 8;
  f32x4 acc[2][2] = {};
  for (int k0 = kb; k0 < kb + Kchunk; k0 += 64) {
#pragma unroll
    for (int h = 0; h < 2; ++h) {
      int r = srow + h * 32;
      *(bf16x8*)(&As[r * LDT2 + scol]) =
          load8rt(Ap, (size_t)(m0 + r) * lda + k0 + scol, ab);
      int rb = n0 + r;
      rb = rb < N ? rb : N - 1;
      size_t bi = (size_t)rb * ldb + k0 + scol;
      *(bf16x8*)(&Bs[r * LDT2 + scol]) = load8rt(Bp0, bi, isbf);
    }
    __syncthreads();
#pragma unroll
    for (int kk2 = 0; kk2 < 2; ++kk2) {
      bf16x8 af[2], bfr[2];
#pragma unroll
      for (int i = 0; i < 2; ++i)
        af[i] = *(const bf16x8*)(&As[(wm * 32 + i * 16 + l16) * LDT2 + kk2 * 32 + quad * 8]);
#pragma unroll
      for (int j = 0; j < 2; ++j)
        bfr[j] = *(const bf16x8*)(&Bs[(wn * 32 + j * 16 + l16) * LDT2 + kk2 * 32 + quad * 8]);
#pragma unroll
      for (int i = 0; i < 2; ++i)
#pragma unroll
        for (int j = 0; j < 2; ++j)
          acc[i][j] = __builtin_amdgcn_mfma_f32_16x16x32_bf16(af[i], bfr[j], acc[i][j], 0, 0, 0);
    }
    __syncthreads();
  }
#pragma unroll
  for (int i = 0; i < 2; ++i) {
#pragma unroll
    for (int j = 0; j < 2; ++j) {
      const int col = n0 + wn * 32 + j * 16 + l16;
      if (col >= N) continue;
      float bv = 0.f;
      if (EPI == EPI_BIAS_RELU || EPI == EPI_BIAS || EPI == EPI_BIAS_SOFTPLUS)
        bv = ldf(biasp, col, isbf);
#pragma unroll
      for (int r = 0; r < 4; ++r) {
        const int row = m0 + wm * 32 + i * 16 + quad * 4 + r;
        size_t idx = (size_t)row * ldc + col;
        float v = acc[i][j][r];
        if (EPI == EPI_STORE) store_t(&C[idx], v);
        else if (EPI == EPI_BIAS_RELU) { v += bv; store_t(&C[idx], v > 0.f ? v : 0.f); }
        else if (EPI == EPI_BIAS) store_t(&C[idx], v + bv);
        else if (EPI == EPI_BIAS_SOFTPLUS) {
          v += bv;
          store_t(&C[idx], (v > 20.f) ? v : log1pf(__expf(v)));
        } else if (EPI == EPI_ATOMIC) {
          atomicAdd((float*)&C[idx], v);
        }
      }
    }
  }
}

// ---- MFMA GEMM 128x128 / BK=64, 2-phase dbuf global_load_lds ---------------
template <typename TC, int EPI>
__global__ __launch_bounds__(256) void gemm128n(
    const int* __restrict__ flagp,
    const bf16* __restrict__ A, int lda,
    const bf16* __restrict__ Bw, int ldb,
    TC* __restrict__ C, int ldc,
    const void* __restrict__ bias,
    int Kchunk) {
  __shared__ __align__(16) __bf16 As[2][128 * 64];
  __shared__ __align__(16) __bf16 Bs[2][128 * 64];
  const int tid = threadIdx.x;
  const int wave = tid >> 6, lane = tid & 63;
  const int quad = lane >> 4, l16 = lane & 15;
  const int wr = wave >> 1, wc = wave & 1;
  int bx = blockIdx.x, by = blockIdx.y;
  const int gx = gridDim.x, gy = gridDim.y;
  if ((gx & 7) == 0) { // XCD swizzle (bijection; gx multiple of 8)
    int id = bx + gx * by;
    int xcd = id & 7, sl = id >> 3;
    by = sl % gy;
    bx = (sl / gy) * 8 + xcd;
  }
  const int m0 = by * 128, n0 = bx * 128;
  const int kb = blockIdx.z * Kchunk;
  const int kend = kb + Kchunk;
  const int lr = lane >> 3;       // 0..7
  const int lc = (lane & 7) * 8;  // col el
  auto STAGE = [&](int buf, int k0) {
#pragma unroll
    for (int rr = 0; rr < 4; ++rr) {
      const int rowb = rr * 32 + wave * 8;
      gld16(A + (size_t)(m0 + rowb + lr) * lda + k0 + lc, &As[buf][rowb * 64]);
      gld16(Bw + (size_t)(n0 + rowb + lr) * ldb + k0 + lc, &Bs[buf][rowb * 64]);
    }
  };
  f32x4 acc[4][4] = {};
  int cur = 0;
  STAGE(0, kb);
  __syncthreads(); // tile 0 resident
  for (int k0 = kb; k0 < kend; k0 += 64) {
    if (k0 + 64 < kend) STAGE(cur ^ 1, k0 + 64); // prefetch next (async)
#pragma unroll
    for (int kk = 0; kk < 2; ++kk) {
      bf16x8 af[4], bfr[4];
#pragma unroll
      for (int i = 0; i < 4; ++i)
        af[i] = *(const bf16x8*)(&As[cur][(wr * 64 + i * 16 + l16) * 64 + kk * 32 + quad * 8]);
#pragma unroll
      for (int j = 0; j < 4; ++j)
        bfr[j] = *(const bf16x8*)(&Bs[cur][(wc * 64 + j * 16 + l16) * 64 + kk * 32 + quad * 8]);
#pragma unroll
      for (int i = 0; i < 4; ++i)
#pragma unroll
        for (int j = 0; j < 4; ++j)
          acc[i][j] = __builtin_amdgcn_mfma_f32_16x16x32_bf16(af[i], bfr[j], acc[i][j], 0, 0, 0);
    }
    __syncthreads(); // drains prefetch (vmcnt 0) + lgkm, barrier
    cur ^= 1;
  }
  const int isbf = *flagp; // bias dtype only
#pragma unroll
  for (int i = 0; i < 4; ++i) {
#pragma unroll
    for (int j = 0; j < 4; ++j) {
      const int col = n0 + wc * 64 + j * 16 + l16;
      float bv = 0.f;
      if (EPI == EPI_BIAS_RELU) bv = ldf(bias, col, isbf);
#pragma unroll
      for (int r = 0; r < 4; ++r) {
        const int row = m0 + wr * 64 + i * 16 + quad * 4 + r;
        size_t idx = (size_t)row * ldc + col;
        float v = acc[i][j][r];
        if (EPI == EPI_STORE) store_t(&C[idx], v);
        else if (EPI == EPI_BIAS_RELU) { v += bv; store_t(&C[idx], v > 0.f ? v : 0.f); }
        else if (EPI == EPI_ATOMIC) atomicAdd((float*)&C[idx], v);
      }
    }
  }
}

// ---- depthwise conv + SiLU, both dirs, bf16 in/out -------------------------
__global__ __launch_bounds__(256) void conv_silu_rt(
    const int* __restrict__ flagp, const bf16* __restrict__ X2b,
    const void* __restrict__ fcw, const void* __restrict__ fcb,
    const void* __restrict__ rcw, const void* __restrict__ rcb,
    bf16* __restrict__ XCb) {
  const int isbf = *flagp;
  const int dir = blockIdx.y >> 2;
  const int d = (blockIdx.y & 3) * 256 + threadIdx.x;
  const int m = blockIdx.x;
  const int t = m & (Nn - 1);
  const void* cw = dir ? rcw : fcw;
  const void* cb = dir ? rcb : fcb;
  float w0 = ldf(cw, d * 4 + 0, isbf), w1 = ldf(cw, d * 4 + 1, isbf);
  float w2 = ldf(cw, d * 4 + 2, isbf), w3 = ldf(cw, d * 4 + 3, isbf);
  float a = ldf(cb, d, isbf);
  const size_t base = (size_t)m * 4096 + (size_t)dir * 2048 + d;
  if (dir == 0) {
    if (t >= 3) a += w0 * to_f(X2b[base - 3 * 4096]);
    if (t >= 2) a += w1 * to_f(X2b[base - 2 * 4096]);
    if (t >= 1) a += w2 * to_f(X2b[base - 1 * 4096]);
    a += w3 * to_f(X2b[base]);
  } else {
    if (t + 3 < Nn) a += w0 * to_f(X2b[base + 3 * 4096]);
    if (t + 2 < Nn) a += w1 * to_f(X2b[base + 2 * 4096]);
    if (t + 1 < Nn) a += w2 * to_f(X2b[base + 1 * 4096]);
    a += w3 * to_f(X2b[base]);
  }
  const float s = a / (1.f + __builtin_amdgcn_exp2f(-a * LOG2E));
  XCb[(size_t)m * 2048 + (size_t)dir * 1024 + d] = __float2bfloat16(s);
}

// ---- selective scan v16: 2 states/lane on lane bits {0,1,5} + all-VALU
// reduce (quad DPP xor1/xor2 + permlane32_swap) + fused delta GEMM.
// 4096 waves = 4/SIMD supply (2x v14); reduce never touches the LDS pipe.
// Block 256 thr = 4 waves = 32 d's; grid (16,32,2) = 1024; LDS 46.5 KB ->
// 3 blk/CU. sY aliases sX (per-wave column ownership, read-then-write).
__global__ __launch_bounds__(256) void scan_gate10(
    const int* __restrict__ flagp,
    const float* __restrict__ DBC0, bf16* __restrict__ XCb, const bf16* __restrict__ X2b,
    const void* __restrict__ fdtw, const void* __restrict__ fdtb,
    const void* __restrict__ rdtw, const void* __restrict__ rdtb,
    const void* __restrict__ fAlog, const void* __restrict__ fDp,
    const void* __restrict__ rAlog, const void* __restrict__ rDp) {
  const int isbf = *flagp;
  const int dir = blockIdx.z;
  const float* DBC = DBC0 + (size_t)dir * Mm * 96;
  const void* dtw = dir ? rdtw : fdtw;
  const void* dtb = dir ? rdtb : fdtb;
  const void* A_log = dir ? rAlog : fAlog;
  const void* Dp = dir ? rDp : fDp;
  __shared__ __align__(16) __bf16 sBC[Nn * 32];          // 8 KB [t][sgp*4+{B0,B1,C0,C1}]
  __shared__ __align__(16) __bf16 sD[Nn * 32];           // 8 KB delta (in-kernel)
  __shared__ __align__(16) __bf16 sX[Nn * 32];           // 8 KB xc; aliased as sY
  __shared__ __align__(16) __bf16 uni[128 * LDT2 + 32 * LDT2]; // 22.5 KB union
  __bf16* At = uni;               // 128*72 (prologue A)
  __bf16* Bt = uni + 128 * LDT2;  //  32*72 (prologue B)
  __bf16* sG = uni;               // 128*32 (main: silu(res))
  const int b = blockIdx.x;
  const int d0 = blockIdx.y * 32;
  const int tid = threadIdx.x; // 0..255
  const size_t rowbase = (size_t)b * Nn;
  const size_t xc_col = (size_t)dir * 1024;
  const int wave = tid >> 6, lane = tid & 63;
  const int quad = lane >> 4, l16 = lane & 15;
  // ---- phase 1: stage At (DBC dt-cols), Bt (dt_w 32 rows), sBC, sX ----
#pragma unroll
  for (int k = 0; k < 8; ++k) {
    int idx = tid + k * 256;            // 0..2047
    int t = idx >> 4, c4 = (idx & 15) * 4;
    float4 v = *(const float4*)(DBC + (rowbase + t) * 96 + c4);
    bf16x4 pv = {cvt1(v.x), cvt1(v.y), cvt1(v.z), cvt1(v.w)};
    *(bf16x4*)&At[t * LDT2 + c4] = pv;
  }
  // sBC: v11-verified interleave [t][ (s>>1)*4 + (B?0:2) + (s&1) ]
#pragma unroll
  for (int k = 0; k < 4; ++k) {
    int idx = tid + k * 256;            // 0..1023
    int t = idx >> 3, c = idx & 7;
    float4 v = *(const float4*)(DBC + (rowbase + t) * 96 + 64 + c * 4);
    const int isC = (c >= 4) ? 2 : 0;
    const int cb4 = (c & 3) * 4;
    float vv[4] = {v.x, v.y, v.z, v.w};
#pragma unroll
    for (int e = 0; e < 4; ++e) {
      int s = cb4 + e;
      sBC[t * 32 + (s >> 1) * 4 + isC + (s & 1)] = cvt1(vv[e]);
    }
  }
  { // Bt: 32 rows x 64 K, one iter of 8-el chunks
    int n = tid >> 3, r8 = (tid & 7) * 8;
    *(bf16x8*)&Bt[n * LDT2 + r8] = load8rt(dtw, (size_t)(d0 + n) * Rr + r8, isbf);
  }
#pragma unroll
  for (int k = 0; k < 2; ++k) {
    int idx = tid + k * 256;            // 0..511
    int t = idx >> 2, h = idx & 3;
    *(uint4*)&sX[t * 32 + h * 8] =
        *(const uint4*)(XCb + (rowbase + t) * 2048 + xc_col + d0 + h * 8);
  }
  __syncthreads();
  // ---- phase 2: delta GEMM 128x32x64 -> softplus -> sD ----
  {
    f32x4 dacc[2][2] = {};
#pragma unroll
    for (int kk = 0; kk < 2; ++kk) {
      bf16x8 af[2], bf_[2];
#pragma unroll
      for (int i = 0; i < 2; ++i)
        af[i] = *(const bf16x8*)(&At[(wave * 32 + i * 16 + l16) * LDT2 + kk * 32 + quad * 8]);
#pragma unroll
      for (int j = 0; j < 2; ++j)
        bf_[j] = *(const bf16x8*)(&Bt[(j * 16 + l16) * LDT2 + kk * 32 + quad * 8]);
#pragma unroll
      for (int i = 0; i < 2; ++i)
#pragma unroll
        for (int j = 0; j < 2; ++j)
          dacc[i][j] = __builtin_amdgcn_mfma_f32_16x16x32_bf16(af[i], bf_[j], dacc[i][j], 0, 0, 0);
    }
#pragma unroll
    for (int i = 0; i < 2; ++i) {
#pragma unroll
      for (int j = 0; j < 2; ++j) {
        const int col = j * 16 + l16;
        const float bv = ldf(dtb, d0 + col, isbf);
#pragma unroll
        for (int r = 0; r < 4; ++r) {
          const int row = wave * 32 + i * 16 + quad * 4 + r;
          float v = dacc[i][j][r] + bv;
          v = (v > 20.f) ? v : log1pf(__expf(v));
          sD[row * 32 + col] = cvt1(v);
        }
      }
    }
  }
  __syncthreads();
  // ---- phase 3: stage sG (silu(res)) over the At/Bt region ----
#pragma unroll
  for (int k = 0; k < 2; ++k) {
    int idx = tid + k * 256;            // 0..511
    int t = idx >> 2, h = idx & 3;
    bf16x8 rv = *(const bf16x8*)(X2b + (rowbase + t) * 4096 + (size_t)dir * 2048 + 1024 + d0 + h * 8);
    bf16x8 gv;
#pragma unroll
    for (int e = 0; e < 8; ++e) {
      float r = bfraw_to_f(rv[e]);
      gv[e] = cvt1(r / (1.f + __builtin_amdgcn_exp2f(-r * LOG2E)));
    }
    *(bf16x8*)&sG[t * 32 + h * 8] = gv;
  }
  __syncthreads();
  // ---- phase 4: scan. sgp on lane bits {0,1,5}; dl on bits [4:2] ----
  const int sgp = (lane & 3) | ((lane >> 3) & 4); // 0..7
  const int dl = (lane >> 2) & 7;                 // 0..7
  const int d_local = wave * 8 + dl;
  const int d = d0 + d_local;
  float A0 = -__expf(ldf(A_log, d * Ss + sgp * 2 + 0, isbf)) * LOG2E;
  float A1 = -__expf(ldf(A_log, d * Ss + sgp * 2 + 1, isbf)) * LOG2E;
  const float dp = ldf(Dp, d, isbf);
  float h0 = 0.f, h1 = 0.f;
  for (int pg = 0; pg < Nn / 4; ++pg) {
    float accs[4], xvs[4];
#pragma unroll
    for (int u = 0; u < 4; ++u) {
      const int p = pg * 4 + u;
      const int t = dir ? (Nn - 1 - p) : p;
      const float dv = bfraw_to_f(sD[t * 32 + d_local]);
      const float xv = bfraw_to_f(sX[t * 32 + d_local]);
      bf16x4 bc = *(const bf16x4*)&sBC[t * 32 + sgp * 4]; // B0,B1,C0,C1
      const float dx = dv * xv;
      h0 = __builtin_amdgcn_exp2f(dv * A0) * h0 + dx * bfraw_to_f(bc[0]);
      h1 = __builtin_amdgcn_exp2f(dv * A1) * h1 + dx * bfraw_to_f(bc[1]);
      accs[u] = h0 * bfraw_to_f(bc[2]) + h1 * bfraw_to_f(bc[3]);
      xvs[u] = xv;
    }
#pragma unroll
    for (int u = 0; u < 4; ++u) {
      float a = accs[u];
      a += quad_xor1(a);           // lane bit 0 (VALU DPP)
      a += quad_xor2(a);           // lane bit 1 (VALU DPP)
      a += lane32_other(a, lane);  // lane bit 5 (VALU permlane32_swap)
      if (sgp == 0) {
        const int p = pg * 4 + u;
        const int t = dir ? (Nn - 1 - p) : p;
        const float g = bfraw_to_f(sG[t * 32 + d_local]);
        sX[t * 32 + d_local] = cvt1((a + xvs[u] * dp) * g); // sY == sX (safe: own column, read-then-write)
      }
    }
  }
  __syncthreads();
  // ---- phase 5: coalesced cooperative writeout (from sX region) ----
#pragma unroll
  for (int k = 0; k < 2; ++k) {
    int idx = tid + k * 256;            // 0..511
    int t = idx >> 2, h = idx & 3;
    *(uint4*)(XCb + (rowbase + t) * 2048 + xc_col + d0 + h * 8) =
        *(const uint4*)&sX[t * 32 + h * 8];
  }
}

// ---- LayerNorm, runtime dtype ---------------------------------------------
template <int MODE>
__global__ __launch_bounds__(256) void ln_rt(const int* __restrict__ flagp,
                                             const float* __restrict__ Z,
                                             const float* __restrict__ Zadd,
                                             const void* __restrict__ g,
                                             const void* __restrict__ bb,
                                             const void* __restrict__ pb,
                                             void* __restrict__ outp,
                                             bf16* __restrict__ outp2) {
  const int isbf = *flagp;
  const int row = blockIdx.x;
  const int tid = threadIdx.x;
  const int c0 = tid * 2;
  const float2* z = (const float2*)(Z + (size_t)row * Ll);
  float2 v = z[tid];
  if (MODE == 1) {
    const float2* za = (const float2*)(Zadd + (size_t)row * Ll);
    float2 a = za[tid];
    v.x += a.x + ldf(pb, c0, isbf);
    v.y += a.y + ldf(pb, c0 + 1, isbf);
  }
  float s = v.x + v.y, q = v.x * v.x + v.y * v.y;
#pragma unroll
  for (int o = 32; o > 0; o >>= 1) {
    s += __shfl_xor(s, o, 64);
    q += __shfl_xor(q, o, 64);
  }
  __shared__ float ss[4], qq[4];
  const int wv = tid >> 6, ln = tid & 63;
  if (ln == 0) { ss[wv] = s; qq[wv] = q; }
  __syncthreads();
  s = ss[0] + ss[1] + ss[2] + ss[3];
  q = qq[0] + qq[1] + qq[2] + qq[3];
  const float mean = s * (1.f / Ll);
  const float var = q * (1.f / Ll) - mean * mean;
  const float rs = rsqrtf(var + 1e-5f);
  const float o0 = (v.x - mean) * rs * ldf(g, c0, isbf) + ldf(bb, c0, isbf);
  const float o1 = (v.y - mean) * rs * ldf(g, c0 + 1, isbf) + ldf(bb, c0 + 1, isbf);
  if (MODE == 0) {
    float* out = (float*)outp;
    out[(size_t)row * Ll + c0] = o0;
    out[(size_t)row * Ll + c0 + 1] = o1;
    outp2[(size_t)row * Ll + c0] = __float2bfloat16(o0);
    outp2[(size_t)row * Ll + c0 + 1] = __float2bfloat16(o1);
  } else {
    if (isbf) {
      bf16* out = (bf16*)outp;
      out[(size_t)row * Ll + c0] = __float2bfloat16(o0);
      out[(size_t)row * Ll + c0 + 1] = __float2bfloat16(o1);
    } else {
      float* out = (float*)outp;
      out[(size_t)row * Ll + c0] = o0;
      out[(size_t)row * Ll + c0 + 1] = o1;
    }
  }
}

// ---- pipeline: 11 dispatches ----------------------------------------------
extern "C" void kernel_launch(void* const* d_in, const int* in_sizes, int n_in, void* d_out,
                              int out_size, void* d_ws, size_t ws_size, hipStream_t stream) {
  char* ws = (char*)d_ws;
  int* flags = (int*)ws;
  bf16* X2b = (bf16*)(ws + 256);                  // [Mm][4096] in-proj out (both dirs)
  bf16* XCb = X2b + (size_t)Mm * 4096;            // [Mm][2048] conv-out / YG
  bf16* Y3b = XCb + (size_t)Mm * 2048;            // [Mm][512]  LN(ZB) bf16
  bf16* Xb = Y3b + (size_t)Mm * 512;              // [Mm][512]  bf16(x)
  bf16* WBin = Xb + (size_t)Mm * 512;             // [4096][512] fused in_w
  bf16* WBout = WBin + (size_t)4096 * 512;        // [512][2048] fused out_w
  bf16* WBpu = WBout + (size_t)512 * 2048;        // [2048][512]
  bf16* WBpl = WBpu + (size_t)2048 * 512;         // [512][2048]
  float* DBC = (float*)(WBpl + (size_t)512 * 2048); // [2][Mm][96]
  float* Z2 = DBC + (size_t)2 * Mm * 96;          // [Mm][512]  (contig after DBC)
  float* ZB = Z2 + (size_t)Mm * 512;              // [Mm][512]
  float* Y3 = ZB + (size_t)Mm * 512;              // [Mm][512]
  bf16* H1 = X2b;                                 // alias: X2b dead after scan
  size_t needed = 256 +
                  2 * ((size_t)Mm * 4096 + (size_t)Mm * 2048 + (size_t)2 * Mm * 512 +
                       (size_t)4096 * 512 + (size_t)512 * 2048 +
                       (size_t)2048 * 512 + (size_t)512 * 2048) +
                  4 * ((size_t)2 * Mm * 96 + (size_t)3 * Mm * 512);
  if (ws_size < needed) return;

  const void* x = d_in[0];
  const dim3 blk(256);

  sniff_kernel<<<dim3(1), blk, 0, stream>>>((const unsigned short*)x, flags);
  // ZB/Xb/zero/weights in one pass
  prep_kernel<<<dim3(4992), blk, 0, stream>>>(
      flags, x, ZB, (unsigned short*)Xb, DBC,
      d_in[1], d_in[10], d_in[9], d_in[18], d_in[19], d_in[21],
      WBin, WBout, WBpu, WBpl);
  // X2b = Xb @ WBin^T   (2048x4096x512), 128-tile 2-phase, grid 32x16
  gemm128n<bf16, EPI_STORE><<<dim3(32, 16), blk, 0, stream>>>(
      flags, Xb, Ll, WBin, Ll, X2b, 4096, nullptr, Ll);
  // XCb = silu(causal_conv(xi)) both dirs
  conv_silu_rt<<<dim3(Mm, 8), blk, 0, stream>>>(flags, X2b, d_in[2], d_in[3],
                                                d_in[11], d_in[12], XCb);
  // DBC[dir] += XCb[:,dir] @ xproj^T  (2048x96x1024, split-K=4, dir-fused)
  gemm_rt<float, EPI_ATOMIC><<<dim3(2, 32, 8), blk, 0, stream>>>(
      flags, XCb, 2048, 1, d_in[4], d_in[13], Dd, 3, 0,
      DBC, 96, nullptr, nullptr, 96, 256, 4, 1024, (size_t)Mm * 96);
  // selective scan + gating (delta GEMM fused) -> YG over XCb (v16)
  scan_gate10<<<dim3(Bb, Dd / 32, 2), blk, 0, stream>>>(
      flags, DBC, XCb, X2b, d_in[5], d_in[6], d_in[14], d_in[15],
      d_in[7], d_in[8], d_in[16], d_in[17]);
  // ZB += XCb @ WBout^T  (2048x512x2048, split-K=4)
  gemm128n<float, EPI_ATOMIC><<<dim3(4, 16, 4), blk, 0, stream>>>(
      flags, XCb, 2048, WBout, 2048, ZB, Ll, nullptr, Ll);
  // y3 = LN(ZB) -> Y3 (f32) + Y3b (bf16)
  ln_rt<0><<<dim3(Mm), blk, 0, stream>>>(flags, ZB, nullptr, d_in[23], d_in[24], nullptr,
                                         (void*)Y3, Y3b);
  // H1 = bf16(relu(Y3b @ WBpu^T + pu_b))  (2048x2048x512)
  gemm128n<bf16, EPI_BIAS_RELU><<<dim3(16, 16), blk, 0, stream>>>(
      flags, Y3b, Ll, WBpu, Ll, H1, Hh, d_in[20], Ll);
  // Z2 += H1 @ WBpl^T  (2048x512x2048, split-K=4; pl_b folded into final LN)
  gemm128n<float, EPI_ATOMIC><<<dim3(4, 16, 4), blk, 0, stream>>>(
      flags, H1, Hh, WBpl, 2048, Z2, Ll, nullptr, Ll);
  // out = LN(Z2 + y3 + pl_b)
  ln_rt<1><<<dim3(Mm), blk, 0, stream>>>(flags, Z2, Y3, d_in[23], d_in[24], d_in[22],
                                         d_out, nullptr);

  (void)in_sizes; (void)n_in; (void)out_size;
}

// Round 15
// 311.934 us; speedup vs baseline: 1.0362x; 1.0362x over previous
//
#include <hip/hip_runtime.h>
#include <hip/hip_bf16.h>
#include <cstdint>

typedef __hip_bfloat16 bf16;

constexpr int Bb = 16, Nn = 128, Ll = 512, Dd = 1024, Ss = 16, Rr = 64, Hh = 2048;
constexpr int Mm = Bb * Nn; // 2048 rows
#define LOG2E 1.44269504088896340736f

using bf16x8 = __attribute__((ext_vector_type(8))) __bf16;
using bf16x4 = __attribute__((ext_vector_type(4))) __bf16;
using f32x4  = __attribute__((ext_vector_type(4))) float;

__device__ __forceinline__ float to_f(float x) { return x; }
__device__ __forceinline__ float to_f(bf16 x) { return __bfloat162float(x); }
__device__ __forceinline__ void store_t(float* p, float v) { *p = v; }
__device__ __forceinline__ void store_t(bf16* p, float v) { *p = __float2bfloat16(v); }
__device__ __forceinline__ __bf16 cvt1(float x) {
  bf16 h = __float2bfloat16(x);
  return *reinterpret_cast<__bf16*>(&h);
}
__device__ __forceinline__ float bfraw_to_f(__bf16 x) {
  bf16 h = *reinterpret_cast<bf16*>(&x);
  return __bfloat162float(h);
}
__device__ __forceinline__ bf16x8 load8(const bf16* p) { return *(const bf16x8*)p; }
__device__ __forceinline__ bf16x8 load8(const float* p) {
  float4 a = *(const float4*)p;
  float4 b = *(const float4*)(p + 4);
  bf16x8 r;
  r[0] = cvt1(a.x); r[1] = cvt1(a.y); r[2] = cvt1(a.z); r[3] = cvt1(a.w);
  r[4] = cvt1(b.x); r[5] = cvt1(b.y); r[6] = cvt1(b.z); r[7] = cvt1(b.w);
  return r;
}
__device__ __forceinline__ bf16x8 load8rt(const void* p, size_t idx, int isbf) {
  if (isbf) return load8((const bf16*)p + idx);
  return load8((const float*)p + idx);
}
__device__ __forceinline__ float ldf(const void* p, int i, int isbf) {
  if (isbf) return __bfloat162float(((const bf16*)p)[i]);
  return ((const float*)p)[i];
}
// async global->LDS 16B: dest = wave-uniform base + lane*16
__device__ __forceinline__ void gld16(const bf16* g, __bf16* l) {
  __builtin_amdgcn_global_load_lds(
      (const __attribute__((address_space(1))) void*)g,
      (__attribute__((address_space(3))) void*)l, 16, 0, 0);
}
// quad butterfly via DPP (VALU pipe -- NOT ds_bpermute/LDS pipe)
#if __has_builtin(__builtin_amdgcn_mov_dpp)
__device__ __forceinline__ float quad_xor1(float v) {
  int r = __builtin_amdgcn_mov_dpp(__builtin_bit_cast(int, v), 0xB1, 0xF, 0xF, true);
  return __builtin_bit_cast(float, r);
}
__device__ __forceinline__ float quad_xor2(float v) {
  int r = __builtin_amdgcn_mov_dpp(__builtin_bit_cast(int, v), 0x4E, 0xF, 0xF, true);
  return __builtin_bit_cast(float, r);
}
#else
__device__ __forceinline__ float quad_xor1(float v) { return __shfl_xor(v, 1, 64); }
__device__ __forceinline__ float quad_xor2(float v) { return __shfl_xor(v, 2, 64); }
#endif

enum { EPI_STORE = 0, EPI_BIAS_RELU = 1, EPI_ADD = 3, EPI_BIAS = 4, EPI_BIAS_SOFTPLUS = 5,
       EPI_ATOMIC = 6 };

// ---- dtype sniffer (trusted) ----------------------------------------------
__global__ void sniff_kernel(const unsigned short* __restrict__ xs, int* __restrict__ flags) {
  const int tid = threadIdx.x;
  int cnt = 0;
  for (int j = 0; j < 64; ++j) {
    int i = tid + j * 256;
    unsigned short u = xs[(size_t)i * 64];
    bf16 h = *reinterpret_cast<bf16*>(&u);
    float v = __bfloat162float(h);
    float a = fabsf(v);
    if (v == 0.f || (a > 0.0009765625f && a < 16.f)) ++cnt;
  }
  __shared__ int sc[256];
  sc[tid] = cnt;
  __syncthreads();
  for (int o = 128; o > 0; o >>= 1) {
    if (tid < o) sc[tid] += sc[tid + o];
    __syncthreads();
  }
  if (tid == 0) flags[0] = (sc[0] > 8192) ? 1 : 0; // 1 = bf16, 0 = f32
}

// ---- prep: ZB=f32(x), Xb=bf16(x), zero DBC|Z2, materialize bf16 weights ----
__global__ __launch_bounds__(256) void prep_kernel(
    const int* __restrict__ flagp, const void* __restrict__ x,
    float* __restrict__ ZB, unsigned short* __restrict__ Xb,
    float* __restrict__ zerop,
    const void* __restrict__ fin, const void* __restrict__ rin,
    const void* __restrict__ fout, const void* __restrict__ rout,
    const void* __restrict__ puw, const void* __restrict__ plw,
    bf16* __restrict__ WBin, bf16* __restrict__ WBout,
    bf16* __restrict__ WBpu, bf16* __restrict__ WBpl) {
  const int isbf = *flagp;
  const int i = blockIdx.x * 256 + threadIdx.x;
  if (i < 262144) { // ZB + Xb (4 el)
    float4 o;
    ushort4 u;
    if (isbf) {
      u = ((const ushort4*)x)[i];
      bf16 h0 = *reinterpret_cast<bf16*>(&u.x), h1 = *reinterpret_cast<bf16*>(&u.y);
      bf16 h2 = *reinterpret_cast<bf16*>(&u.z), h3 = *reinterpret_cast<bf16*>(&u.w);
      o = float4{__bfloat162float(h0), __bfloat162float(h1),
                 __bfloat162float(h2), __bfloat162float(h3)};
    } else {
      o = ((const float4*)x)[i];
      bf16 h0 = __float2bfloat16(o.x), h1 = __float2bfloat16(o.y);
      bf16 h2 = __float2bfloat16(o.z), h3 = __float2bfloat16(o.w);
      u = ushort4{*(unsigned short*)&h0, *(unsigned short*)&h1,
                  *(unsigned short*)&h2, *(unsigned short*)&h3};
    }
    ((float4*)ZB)[i] = o;
    ((ushort4*)Xb)[i] = u;
  } else if (i < 622592) { // zero DBC|Z2
    ((float4*)zerop)[i - 262144] = float4{0.f, 0.f, 0.f, 0.f};
  } else { // weights, 8-el chunks
    const int j = i - 622592;
    const void* src;
    bf16* dst;
    int si;
    if (j < 131072) { src = fin; si = j; dst = WBin + (size_t)si * 8; }
    else if (j < 262144) { src = rin; si = j - 131072; dst = WBin + (size_t)1048576 + (size_t)si * 8; }
    else if (j < 393216) { src = puw; si = j - 262144; dst = WBpu + (size_t)si * 8; }
    else if (j < 524288) { src = plw; si = j - 393216; dst = WBpl + (size_t)si * 8; }
    else if (j < 589824) { // f_out [512][1024] -> WBout[n][0..1023]
      src = fout; si = j - 524288;
      int e = si * 8;
      dst = WBout + (size_t)(e >> 10) * 2048 + (e & 1023);
    } else {               // r_out [512][1024] -> WBout[n][1024..2047]
      src = rout; si = j - 589824;
      int e = si * 8;
      dst = WBout + (size_t)(e >> 10) * 2048 + 1024 + (e & 1023);
    }
    *(bf16x8*)dst = load8rt(src, (size_t)si * 8, isbf);
  }
}

constexpr int LDT2 = 72; // anti-conflict row stride (144 B)

// ---- MFMA GEMM 64x64 tile (trusted core): xproj ---------------------------
template <typename TC, int EPI>
__global__ __launch_bounds__(256) void gemm_rt(
    const int* __restrict__ flagp,
    const void* __restrict__ A, int lda, int abf,
    const void* __restrict__ Bw, const void* __restrict__ Bw2, int ldb,
    int bmode, int bsplit,
    TC* __restrict__ C, int ldc,
    const void* __restrict__ bias, const void* __restrict__ bias2,
    int N, int Kchunk, int zk, size_t a_doff, size_t c_doff) {
  const int isbf = *flagp;
  const int ab = (abf == 2) ? isbf : abf;
  __shared__ __align__(16) __bf16 As[64 * LDT2];
  __shared__ __align__(16) __bf16 Bs[64 * LDT2];
  const int tid = threadIdx.x;
  const int wave = tid >> 6, lane = tid & 63;
  const int quad = lane >> 4, l16 = lane & 15;
  const int wm = wave & 1, wn = wave >> 1;
  int bx = blockIdx.x, by = blockIdx.y;
  const int gx = gridDim.x, gy = gridDim.y;
  if ((gx & 7) == 0) {
    int id = bx + gx * by;
    int xcd = id & 7, sl = id >> 3;
    by = sl % gy;
    bx = (sl / gy) * 8 + xcd;
  }
  int zsl = blockIdx.z;
  const void* Ap = A;
  const void* Bp0 = Bw;
  const void* biasp = bias;
  if (bmode == 3) {
    const int dir = zsl / zk;
    zsl = zsl % zk;
    if (dir) {
      Ap = (const char*)A + a_doff * (size_t)(ab ? 2 : 4);
      C += c_doff;
      Bp0 = Bw2;
      biasp = bias2;
    }
  }
  const int m0 = by * 64, n0 = bx * 64;
  const int kb = zsl * Kchunk;
  const int srow = tid >> 3;
  const int scol = (tid & 7) * 8;
  f32x4 acc[2][2] = {};
  for (int k0 = kb; k0 < kb + Kchunk; k0 += 64) {
#pragma unroll
    for (int h = 0; h < 2; ++h) {
      int r = srow + h * 32;
      *(bf16x8*)(&As[r * LDT2 + scol]) =
          load8rt(Ap, (size_t)(m0 + r) * lda + k0 + scol, ab);
      int rb = n0 + r;
      rb = rb < N ? rb : N - 1;
      size_t bi = (size_t)rb * ldb + k0 + scol;
      *(bf16x8*)(&Bs[r * LDT2 + scol]) = load8rt(Bp0, bi, isbf);
    }
    __syncthreads();
#pragma unroll
    for (int kk2 = 0; kk2 < 2; ++kk2) {
      bf16x8 af[2], bfr[2];
#pragma unroll
      for (int i = 0; i < 2; ++i)
        af[i] = *(const bf16x8*)(&As[(wm * 32 + i * 16 + l16) * LDT2 + kk2 * 32 + quad * 8]);
#pragma unroll
      for (int j = 0; j < 2; ++j)
        bfr[j] = *(const bf16x8*)(&Bs[(wn * 32 + j * 16 + l16) * LDT2 + kk2 * 32 + quad * 8]);
#pragma unroll
      for (int i = 0; i < 2; ++i)
#pragma unroll
        for (int j = 0; j < 2; ++j)
          acc[i][j] = __builtin_amdgcn_mfma_f32_16x16x32_bf16(af[i], bfr[j], acc[i][j], 0, 0, 0);
    }
    __syncthreads();
  }
#pragma unroll
  for (int i = 0; i < 2; ++i) {
#pragma unroll
    for (int j = 0; j < 2; ++j) {
      const int col = n0 + wn * 32 + j * 16 + l16;
      if (col >= N) continue;
      float bv = 0.f;
      if (EPI == EPI_BIAS_RELU || EPI == EPI_BIAS || EPI == EPI_BIAS_SOFTPLUS)
        bv = ldf(biasp, col, isbf);
#pragma unroll
      for (int r = 0; r < 4; ++r) {
        const int row = m0 + wm * 32 + i * 16 + quad * 4 + r;
        size_t idx = (size_t)row * ldc + col;
        float v = acc[i][j][r];
        if (EPI == EPI_STORE) store_t(&C[idx], v);
        else if (EPI == EPI_BIAS_RELU) { v += bv; store_t(&C[idx], v > 0.f ? v : 0.f); }
        else if (EPI == EPI_BIAS) store_t(&C[idx], v + bv);
        else if (EPI == EPI_BIAS_SOFTPLUS) {
          v += bv;
          store_t(&C[idx], (v > 20.f) ? v : log1pf(__expf(v)));
        } else if (EPI == EPI_ATOMIC) {
          atomicAdd((float*)&C[idx], v);
        }
      }
    }
  }
}

// ---- MFMA GEMM 128x128 / BK=64, 2-phase dbuf global_load_lds ---------------
template <typename TC, int EPI>
__global__ __launch_bounds__(256) void gemm128n(
    const int* __restrict__ flagp,
    const bf16* __restrict__ A, int lda,
    const bf16* __restrict__ Bw, int ldb,
    TC* __restrict__ C, int ldc,
    const void* __restrict__ bias,
    int Kchunk) {
  __shared__ __align__(16) __bf16 As[2][128 * 64];
  __shared__ __align__(16) __bf16 Bs[2][128 * 64];
  const int tid = threadIdx.x;
  const int wave = tid >> 6, lane = tid & 63;
  const int quad = lane >> 4, l16 = lane & 15;
  const int wr = wave >> 1, wc = wave & 1;
  int bx = blockIdx.x, by = blockIdx.y;
  const int gx = gridDim.x, gy = gridDim.y;
  if ((gx & 7) == 0) { // XCD swizzle (bijection; gx multiple of 8)
    int id = bx + gx * by;
    int xcd = id & 7, sl = id >> 3;
    by = sl % gy;
    bx = (sl / gy) * 8 + xcd;
  }
  const int m0 = by * 128, n0 = bx * 128;
  const int kb = blockIdx.z * Kchunk;
  const int kend = kb + Kchunk;
  const int lr = lane >> 3;       // 0..7
  const int lc = (lane & 7) * 8;  // col el
  auto STAGE = [&](int buf, int k0) {
#pragma unroll
    for (int rr = 0; rr < 4; ++rr) {
      const int rowb = rr * 32 + wave * 8;
      gld16(A + (size_t)(m0 + rowb + lr) * lda + k0 + lc, &As[buf][rowb * 64]);
      gld16(Bw + (size_t)(n0 + rowb + lr) * ldb + k0 + lc, &Bs[buf][rowb * 64]);
    }
  };
  f32x4 acc[4][4] = {};
  int cur = 0;
  STAGE(0, kb);
  __syncthreads(); // tile 0 resident
  for (int k0 = kb; k0 < kend; k0 += 64) {
    if (k0 + 64 < kend) STAGE(cur ^ 1, k0 + 64); // prefetch next (async)
#pragma unroll
    for (int kk = 0; kk < 2; ++kk) {
      bf16x8 af[4], bfr[4];
#pragma unroll
      for (int i = 0; i < 4; ++i)
        af[i] = *(const bf16x8*)(&As[cur][(wr * 64 + i * 16 + l16) * 64 + kk * 32 + quad * 8]);
#pragma unroll
      for (int j = 0; j < 4; ++j)
        bfr[j] = *(const bf16x8*)(&Bs[cur][(wc * 64 + j * 16 + l16) * 64 + kk * 32 + quad * 8]);
#pragma unroll
      for (int i = 0; i < 4; ++i)
#pragma unroll
        for (int j = 0; j < 4; ++j)
          acc[i][j] = __builtin_amdgcn_mfma_f32_16x16x32_bf16(af[i], bfr[j], acc[i][j], 0, 0, 0);
    }
    __syncthreads(); // drains prefetch (vmcnt 0) + lgkm, barrier
    cur ^= 1;
  }
  const int isbf = *flagp; // bias dtype only
#pragma unroll
  for (int i = 0; i < 4; ++i) {
#pragma unroll
    for (int j = 0; j < 4; ++j) {
      const int col = n0 + wc * 64 + j * 16 + l16;
      float bv = 0.f;
      if (EPI == EPI_BIAS_RELU) bv = ldf(bias, col, isbf);
#pragma unroll
      for (int r = 0; r < 4; ++r) {
        const int row = m0 + wr * 64 + i * 16 + quad * 4 + r;
        size_t idx = (size_t)row * ldc + col;
        float v = acc[i][j][r];
        if (EPI == EPI_STORE) store_t(&C[idx], v);
        else if (EPI == EPI_BIAS_RELU) { v += bv; store_t(&C[idx], v > 0.f ? v : 0.f); }
        else if (EPI == EPI_ATOMIC) atomicAdd((float*)&C[idx], v);
      }
    }
  }
}

// ---- depthwise conv + SiLU, both dirs, bf16 in/out -------------------------
__global__ __launch_bounds__(256) void conv_silu_rt(
    const int* __restrict__ flagp, const bf16* __restrict__ X2b,
    const void* __restrict__ fcw, const void* __restrict__ fcb,
    const void* __restrict__ rcw, const void* __restrict__ rcb,
    bf16* __restrict__ XCb) {
  const int isbf = *flagp;
  const int dir = blockIdx.y >> 2;
  const int d = (blockIdx.y & 3) * 256 + threadIdx.x;
  const int m = blockIdx.x;
  const int t = m & (Nn - 1);
  const void* cw = dir ? rcw : fcw;
  const void* cb = dir ? rcb : fcb;
  float w0 = ldf(cw, d * 4 + 0, isbf), w1 = ldf(cw, d * 4 + 1, isbf);
  float w2 = ldf(cw, d * 4 + 2, isbf), w3 = ldf(cw, d * 4 + 3, isbf);
  float a = ldf(cb, d, isbf);
  const size_t base = (size_t)m * 4096 + (size_t)dir * 2048 + d;
  if (dir == 0) {
    if (t >= 3) a += w0 * to_f(X2b[base - 3 * 4096]);
    if (t >= 2) a += w1 * to_f(X2b[base - 2 * 4096]);
    if (t >= 1) a += w2 * to_f(X2b[base - 1 * 4096]);
    a += w3 * to_f(X2b[base]);
  } else {
    if (t + 3 < Nn) a += w0 * to_f(X2b[base + 3 * 4096]);
    if (t + 2 < Nn) a += w1 * to_f(X2b[base + 2 * 4096]);
    if (t + 1 < Nn) a += w2 * to_f(X2b[base + 1 * 4096]);
    a += w3 * to_f(X2b[base]);
  }
  const float s = a / (1.f + __builtin_amdgcn_exp2f(-a * LOG2E));
  XCb[(size_t)m * 2048 + (size_t)dir * 1024 + d] = __float2bfloat16(s);
}

// ---- selective scan v15 (R13 best): v14 structure + FUSED delta GEMM ------
// Block (b, 64 d's, dir). Prologue computes delta = softplus(DBC[:, :64] @
// dt_w[d0:d0+64]^T + dt_b) with 16 MFMA/wave (trusted 64x64-core fragment
// pattern, LDT2 stride) straight into sD -- the standalone DELTA GEMM
// dispatch and its 16 MB global round-trip are eliminated. LDS unions the
// prologue A/B tiles (27 KB) with sG+sY (32 KB) => 72 KB, 2 blk/CU.
// Scan: 4 states/lane, state-group on lane bits [1:0]+[5:4] quad (sg =
// lane&3 layout of v14), reduce = 2x VALU DPP quad_perm (no LDS pipe).
__global__ __launch_bounds__(256) void scan_gate9(
    const int* __restrict__ flagp,
    const float* __restrict__ DBC0, bf16* __restrict__ XCb, const bf16* __restrict__ X2b,
    const void* __restrict__ fdtw, const void* __restrict__ fdtb,
    const void* __restrict__ rdtw, const void* __restrict__ rdtb,
    const void* __restrict__ fAlog, const void* __restrict__ fDp,
    const void* __restrict__ rAlog, const void* __restrict__ rDp) {
  const int isbf = *flagp;
  const int dir = blockIdx.z;
  const float* DBC = DBC0 + (size_t)dir * Mm * 96;
  const void* dtw = dir ? rdtw : fdtw;
  const void* dtb = dir ? rdtb : fdtb;
  const void* A_log = dir ? rAlog : fAlog;
  const void* Dp = dir ? rDp : fDp;
  __shared__ __align__(16) __bf16 sBC[Nn * 32];        // 8 KB
  __shared__ __align__(16) __bf16 sD[Nn * 64];         // 16 KB (delta, in-kernel)
  __shared__ __align__(16) __bf16 sX[Nn * 64];         // 16 KB
  __shared__ __align__(16) __bf16 uni[2 * Nn * 64];    // 32 KB union region
  __bf16* At = uni;                 // 128*72 el = 18 KB (prologue)
  __bf16* Bt = uni + 128 * LDT2;    //  64*72 el =  9 KB (prologue)
  __bf16* sG = uni;                 // 128*64 el = 16 KB (main)
  __bf16* sY = uni + Nn * 64;       // 128*64 el = 16 KB (main)
  const int b = blockIdx.x;
  const int d0 = blockIdx.y * 64;
  const int tid = threadIdx.x; // 0..255
  const size_t rowbase = (size_t)b * Nn;
  const size_t xc_col = (size_t)dir * 1024;
  const int wave = tid >> 6, lane = tid & 63;
  const int quad = lane >> 4, l16 = lane & 15;
  // ---- phase 1: stage At (DBC dt-cols), Bt (dt_w), sBC, sX ----
#pragma unroll
  for (int k = 0; k < 8; ++k) {
    int idx = tid + k * 256;            // 0..2047 (quad-loads)
    int t = idx >> 4, c4 = (idx & 15) * 4;
    float4 v = *(const float4*)(DBC + (rowbase + t) * 96 + c4);
    bf16x4 pv = {cvt1(v.x), cvt1(v.y), cvt1(v.z), cvt1(v.w)};
    *(bf16x4*)&At[t * LDT2 + c4] = pv;
  }
#pragma unroll
  for (int k = 0; k < 4; ++k) {
    int idx = tid + k * 256;            // 0..1023
    int t = idx >> 3, c = idx & 7;
    float4 v = *(const float4*)(DBC + (rowbase + t) * 96 + 64 + c * 4);
    bf16x4 pv = {cvt1(v.x), cvt1(v.y), cvt1(v.z), cvt1(v.w)};
    int dst = (c < 4) ? (t * 32 + c * 8) : (t * 32 + (c - 4) * 8 + 4);
    *(bf16x4*)&sBC[dst] = pv;
  }
#pragma unroll
  for (int k = 0; k < 2; ++k) {
    int c8 = tid + k * 256;             // 0..511 (8-el chunks)
    int n = c8 >> 3, r8 = (c8 & 7) * 8;
    *(bf16x8*)&Bt[n * LDT2 + r8] = load8rt(dtw, (size_t)(d0 + n) * Rr + r8, isbf);
  }
#pragma unroll
  for (int k = 0; k < 4; ++k) {
    int idx = tid + k * 256;            // 0..1023
    int t = idx >> 3, h = idx & 7;
    *(uint4*)&sX[t * 64 + h * 8] =
        *(const uint4*)(XCb + (rowbase + t) * 2048 + xc_col + d0 + h * 8);
  }
  __syncthreads();
  // ---- phase 2: delta GEMM 128x64x64 -> softplus -> sD ----
  {
    f32x4 dacc[2][4] = {};
#pragma unroll
    for (int kk = 0; kk < 2; ++kk) {
      bf16x8 af[2], bf_[4];
#pragma unroll
      for (int i = 0; i < 2; ++i)
        af[i] = *(const bf16x8*)(&At[(wave * 32 + i * 16 + l16) * LDT2 + kk * 32 + quad * 8]);
#pragma unroll
      for (int j = 0; j < 4; ++j)
        bf_[j] = *(const bf16x8*)(&Bt[(j * 16 + l16) * LDT2 + kk * 32 + quad * 8]);
#pragma unroll
      for (int i = 0; i < 2; ++i)
#pragma unroll
        for (int j = 0; j < 4; ++j)
          dacc[i][j] = __builtin_amdgcn_mfma_f32_16x16x32_bf16(af[i], bf_[j], dacc[i][j], 0, 0, 0);
    }
#pragma unroll
    for (int i = 0; i < 2; ++i) {
#pragma unroll
      for (int j = 0; j < 4; ++j) {
        const int col = j * 16 + l16;
        const float bv = ldf(dtb, d0 + col, isbf);
#pragma unroll
        for (int r = 0; r < 4; ++r) {
          const int row = wave * 32 + i * 16 + quad * 4 + r;
          float v = dacc[i][j][r] + bv;
          v = (v > 20.f) ? v : log1pf(__expf(v));
          sD[row * 64 + col] = cvt1(v);
        }
      }
    }
  }
  __syncthreads();
  // ---- phase 3: stage sG (silu(res)) over the At region ----
#pragma unroll
  for (int k = 0; k < 4; ++k) {
    int idx = tid + k * 256;            // 0..1023
    int t = idx >> 3, h = idx & 7;
    bf16x8 rv = *(const bf16x8*)(X2b + (rowbase + t) * 4096 + (size_t)dir * 2048 + 1024 + d0 + h * 8);
    bf16x8 gv;
#pragma unroll
    for (int e = 0; e < 8; ++e) {
      float r = bfraw_to_f(rv[e]);
      gv[e] = cvt1(r / (1.f + __builtin_amdgcn_exp2f(-r * LOG2E)));
    }
    *(bf16x8*)&sG[t * 64 + h * 8] = gv;
  }
  __syncthreads();
  // ---- phase 4: scan (v14 structure: low-bit state groups, DPP reduce) ----
  const int wv = wave;
  const int sg = lane & 3, dl = lane >> 2; // state-group LOW bits, 16 d's/wave
  const int d_local = wv * 16 + dl;
  const int d = d0 + d_local;
  float A_[4];
#pragma unroll
  for (int j = 0; j < 4; ++j)
    A_[j] = -__expf(ldf(A_log, d * Ss + sg * 4 + j, isbf)) * LOG2E;
  const float dp = ldf(Dp, d, isbf);
  float h0 = 0.f, h1 = 0.f, h2 = 0.f, h3 = 0.f;
  for (int pg = 0; pg < Nn / 4; ++pg) {
    float accs[4], xvs[4];
#pragma unroll
    for (int u = 0; u < 4; ++u) {
      const int p = pg * 4 + u;
      const int t = dir ? (Nn - 1 - p) : p;
      const float dv = bfraw_to_f(sD[t * 64 + d_local]);
      const float xv = bfraw_to_f(sX[t * 64 + d_local]);
      bf16x8 bc = *(const bf16x8*)&sBC[t * 32 + sg * 8]; // B[0..3] | C[0..3]
      const float dx = dv * xv;
      h0 = __builtin_amdgcn_exp2f(dv * A_[0]) * h0 + dx * bfraw_to_f(bc[0]);
      h1 = __builtin_amdgcn_exp2f(dv * A_[1]) * h1 + dx * bfraw_to_f(bc[1]);
      h2 = __builtin_amdgcn_exp2f(dv * A_[2]) * h2 + dx * bfraw_to_f(bc[2]);
      h3 = __builtin_amdgcn_exp2f(dv * A_[3]) * h3 + dx * bfraw_to_f(bc[3]);
      accs[u] = h0 * bfraw_to_f(bc[4]) + h1 * bfraw_to_f(bc[5]) +
                h2 * bfraw_to_f(bc[6]) + h3 * bfraw_to_f(bc[7]);
      xvs[u] = xv;
    }
#pragma unroll
    for (int u = 0; u < 4; ++u) {
      float a = accs[u];
      a += quad_xor1(a);   // VALU DPP
      a += quad_xor2(a);   // VALU DPP
      if (sg == 0) {
        const int p = pg * 4 + u;
        const int t = dir ? (Nn - 1 - p) : p;
        const float g = bfraw_to_f(sG[t * 64 + d_local]);
        sY[t * 64 + d_local] = cvt1((a + xvs[u] * dp) * g);
      }
    }
  }
  __syncthreads();
  // ---- phase 5: coalesced cooperative writeout ----
#pragma unroll
  for (int k = 0; k < 4; ++k) {
    int idx = tid + k * 256;            // 0..1023
    int t = idx >> 3, h = idx & 7;
    *(uint4*)(XCb + (rowbase + t) * 2048 + xc_col + d0 + h * 8) =
        *(const uint4*)&sY[t * 64 + h * 8];
  }
}

// ---- LayerNorm, runtime dtype ---------------------------------------------
template <int MODE>
__global__ __launch_bounds__(256) void ln_rt(const int* __restrict__ flagp,
                                             const float* __restrict__ Z,
                                             const float* __restrict__ Zadd,
                                             const void* __restrict__ g,
                                             const void* __restrict__ bb,
                                             const void* __restrict__ pb,
                                             void* __restrict__ outp,
                                             bf16* __restrict__ outp2) {
  const int isbf = *flagp;
  const int row = blockIdx.x;
  const int tid = threadIdx.x;
  const int c0 = tid * 2;
  const float2* z = (const float2*)(Z + (size_t)row * Ll);
  float2 v = z[tid];
  if (MODE == 1) {
    const float2* za = (const float2*)(Zadd + (size_t)row * Ll);
    float2 a = za[tid];
    v.x += a.x + ldf(pb, c0, isbf);
    v.y += a.y + ldf(pb, c0 + 1, isbf);
  }
  float s = v.x + v.y, q = v.x * v.x + v.y * v.y;
#pragma unroll
  for (int o = 32; o > 0; o >>= 1) {
    s += __shfl_xor(s, o, 64);
    q += __shfl_xor(q, o, 64);
  }
  __shared__ float ss[4], qq[4];
  const int wv = tid >> 6, ln = tid & 63;
  if (ln == 0) { ss[wv] = s; qq[wv] = q; }
  __syncthreads();
  s = ss[0] + ss[1] + ss[2] + ss[3];
  q = qq[0] + qq[1] + qq[2] + qq[3];
  const float mean = s * (1.f / Ll);
  const float var = q * (1.f / Ll) - mean * mean;
  const float rs = rsqrtf(var + 1e-5f);
  const float o0 = (v.x - mean) * rs * ldf(g, c0, isbf) + ldf(bb, c0, isbf);
  const float o1 = (v.y - mean) * rs * ldf(g, c0 + 1, isbf) + ldf(bb, c0 + 1, isbf);
  if (MODE == 0) {
    float* out = (float*)outp;
    out[(size_t)row * Ll + c0] = o0;
    out[(size_t)row * Ll + c0 + 1] = o1;
    outp2[(size_t)row * Ll + c0] = __float2bfloat16(o0);
    outp2[(size_t)row * Ll + c0 + 1] = __float2bfloat16(o1);
  } else {
    if (isbf) {
      bf16* out = (bf16*)outp;
      out[(size_t)row * Ll + c0] = __float2bfloat16(o0);
      out[(size_t)row * Ll + c0 + 1] = __float2bfloat16(o1);
    } else {
      float* out = (float*)outp;
      out[(size_t)row * Ll + c0] = o0;
      out[(size_t)row * Ll + c0 + 1] = o1;
    }
  }
}

// ---- pipeline: 12 dispatches ----------------------------------------------
extern "C" void kernel_launch(void* const* d_in, const int* in_sizes, int n_in, void* d_out,
                              int out_size, void* d_ws, size_t ws_size, hipStream_t stream) {
  char* ws = (char*)d_ws;
  int* flags = (int*)ws;
  bf16* X2b = (bf16*)(ws + 256);                  // [Mm][4096] in-proj out (both dirs)
  bf16* XCb = X2b + (size_t)Mm * 4096;            // [Mm][2048] conv-out / YG
  bf16* Y3b = XCb + (size_t)Mm * 2048;            // [Mm][512]  LN(ZB) bf16
  bf16* Xb = Y3b + (size_t)Mm * 512;              // [Mm][512]  bf16(x)
  bf16* WBin = Xb + (size_t)Mm * 512;             // [4096][512] fused in_w
  bf16* WBout = WBin + (size_t)4096 * 512;        // [512][2048] fused out_w
  bf16* WBpu = WBout + (size_t)512 * 2048;        // [2048][512]
  bf16* WBpl = WBpu + (size_t)2048 * 512;         // [512][2048]
  float* DBC = (float*)(WBpl + (size_t)512 * 2048); // [2][Mm][96]
  float* Z2 = DBC + (size_t)2 * Mm * 96;          // [Mm][512]  (contig after DBC)
  float* ZB = Z2 + (size_t)Mm * 512;              // [Mm][512]
  float* Y3 = ZB + (size_t)Mm * 512;              // [Mm][512]
  bf16* H1 = X2b;                                 // alias: X2b dead after scan
  size_t needed = 256 +
                  2 * ((size_t)Mm * 4096 + (size_t)Mm * 2048 + (size_t)2 * Mm * 512 +
                       (size_t)4096 * 512 + (size_t)512 * 2048 +
                       (size_t)2048 * 512 + (size_t)512 * 2048) +
                  4 * ((size_t)2 * Mm * 96 + (size_t)3 * Mm * 512);
  if (ws_size < needed) return;

  const void* x = d_in[0];
  const dim3 blk(256);

  sniff_kernel<<<dim3(1), blk, 0, stream>>>((const unsigned short*)x, flags);
  // ZB/Xb/zero/weights in one pass: 262144 + 360448 + 655360 = 1277952 thr
  prep_kernel<<<dim3(4992), blk, 0, stream>>>(
      flags, x, ZB, (unsigned short*)Xb, DBC,
      d_in[1], d_in[10], d_in[9], d_in[18], d_in[19], d_in[21],
      WBin, WBout, WBpu, WBpl);
  // X2b = Xb @ WBin^T   (2048x4096x512), 128-tile 2-phase, grid 32x16
  gemm128n<bf16, EPI_STORE><<<dim3(32, 16), blk, 0, stream>>>(
      flags, Xb, Ll, WBin, Ll, X2b, 4096, nullptr, Ll);
  // XCb = silu(causal_conv(xi)) both dirs
  conv_silu_rt<<<dim3(Mm, 8), blk, 0, stream>>>(flags, X2b, d_in[2], d_in[3],
                                                d_in[11], d_in[12], XCb);
  // DBC[dir] += XCb[:,dir] @ xproj^T  (2048x96x1024, split-K=4, dir-fused)
  gemm_rt<float, EPI_ATOMIC><<<dim3(2, 32, 8), blk, 0, stream>>>(
      flags, XCb, 2048, 1, d_in[4], d_in[13], Dd, 3, 0,
      DBC, 96, nullptr, nullptr, 96, 256, 4, 1024, (size_t)Mm * 96);
  // selective scan + gating (delta GEMM fused in-kernel) -> YG over XCb (v15)
  scan_gate9<<<dim3(Bb, Dd / 64, 2), blk, 0, stream>>>(
      flags, DBC, XCb, X2b, d_in[5], d_in[6], d_in[14], d_in[15],
      d_in[7], d_in[8], d_in[16], d_in[17]);
  // ZB += XCb @ WBout^T  (2048x512x2048, split-K=4)
  gemm128n<float, EPI_ATOMIC><<<dim3(4, 16, 4), blk, 0, stream>>>(
      flags, XCb, 2048, WBout, 2048, ZB, Ll, nullptr, Ll);
  // y3 = LN(ZB) -> Y3 (f32) + Y3b (bf16)
  ln_rt<0><<<dim3(Mm), blk, 0, stream>>>(flags, ZB, nullptr, d_in[23], d_in[24], nullptr,
                                         (void*)Y3, Y3b);
  // H1 = bf16(relu(Y3b @ WBpu^T + pu_b))  (2048x2048x512)
  gemm128n<bf16, EPI_BIAS_RELU><<<dim3(16, 16), blk, 0, stream>>>(
      flags, Y3b, Ll, WBpu, Ll, H1, Hh, d_in[20], Ll);
  // Z2 += H1 @ WBpl^T  (2048x512x2048, split-K=4; pl_b folded into final LN)
  gemm128n<float, EPI_ATOMIC><<<dim3(4, 16, 4), blk, 0, stream>>>(
      flags, H1, Hh, WBpl, 2048, Z2, Ll, nullptr, Ll);
  // out = LN(Z2 + y3 + pl_b)
  ln_rt<1><<<dim3(Mm), blk, 0, stream>>>(flags, Z2, Y3, d_in[23], d_in[24], d_in[22],
                                         d_out, nullptr);

  (void)in_sizes; (void)n_in; (void)out_size;
}